// Round 1
// baseline (2383.596 us; speedup 1.0000x reference)
//
#include <hip/hip_runtime.h>

typedef unsigned short u16;
typedef __attribute__((ext_vector_type(4))) float f4;
typedef __attribute__((ext_vector_type(8))) short bf16x8;

#define DEV static __device__ __forceinline__

DEV u16 f2bf(float f){
  unsigned u = __builtin_bit_cast(unsigned, f);
  u += 0x7FFFu + ((u >> 16) & 1u);           // RNE
  return (u16)(u >> 16);
}
DEV float bf2f(u16 h){
  unsigned u = ((unsigned)h) << 16;
  return __builtin_bit_cast(float, u);
}
DEV unsigned pack2(float a, float b){
  return (unsigned)f2bf(a) | ((unsigned)f2bf(b) << 16);
}
DEV float gelu_f(float x){ return 0.5f * x * (1.0f + erff(x * 0.70710678118654752f)); }

// ---------------------------------------------------------------------------
// Weight pre-swizzle into MFMA fragment-linear order:
//  element B[k][n] of a (BK=32 x BN-tile=16) tile lives at
//  ((kt*NT + nt)*64 + quad*16 + l15)*8 + j   with k = kt*32+quad*8+j, n = nt*16+l15
// so a wave's b_frag load is lane-contiguous 16B (conflict-free ds_read_b128).
// W_in_sw: kt in [0,24), nt in [0,16).  Wkv_sw: [half][kt<8][nt<16].
// ---------------------------------------------------------------------------
__global__ void k_swizzle(const float* __restrict__ Win, const float* __restrict__ Wk,
                          const float* __restrict__ Wv, u16* __restrict__ Win_sw,
                          u16* __restrict__ Wkv_sw){
  int gid = blockIdx.x * 256 + threadIdx.x;
  const int TW = 24 * 16 * 64;
  if (gid < TW){
    int lane = gid & 63, nt = (gid >> 6) & 15, kt = gid >> 10;
    int l15 = lane & 15, quad = lane >> 4;
    int n = nt * 16 + l15;
    int kb = kt * 32 + quad * 8;
    float v[8];
#pragma unroll
    for (int j = 0; j < 8; ++j) v[j] = Win[(size_t)(kb + j) * 256 + n];
    int4 pk; pk.x = (int)pack2(v[0], v[1]); pk.y = (int)pack2(v[2], v[3]);
    pk.z = (int)pack2(v[4], v[5]); pk.w = (int)pack2(v[6], v[7]);
    *(int4*)(Win_sw + (size_t)gid * 8) = pk;
  } else {
    int g2 = gid - TW;
    const int TK = 2 * 8 * 16 * 64;
    if (g2 < TK){
      int lane = g2 & 63, nt = (g2 >> 6) & 15, kt = (g2 >> 10) & 7, half = g2 >> 13;
      int l15 = lane & 15, quad = lane >> 4;
      const float* W = half ? Wv : Wk;
      int n = nt * 16 + l15;
      int kb = kt * 32 + quad * 8;
      float v[8];
#pragma unroll
      for (int j = 0; j < 8; ++j) v[j] = W[(size_t)(kb + j) * 256 + n];
      int4 pk; pk.x = (int)pack2(v[0], v[1]); pk.y = (int)pack2(v[2], v[3]);
      pk.z = (int)pack2(v[4], v[5]); pk.w = (int)pack2(v[6], v[7]);
      *(int4*)(Wkv_sw + (size_t)g2 * 8) = pk;
    }
  }
}

// ---------------------------------------------------------------------------
// A1: x = gelu(ln(node_emb @ W_in + b_in)) -> bf16 [N,256]
// block 256 (4 waves). BM=64 rows, BN=256 (full width so LN is block-local).
// wave w owns cols [w*64, w*64+64): 4 row-tiles x 4 col-tiles, 16 MFMA/step.
// ---------------------------------------------------------------------------
__global__ __launch_bounds__(256) void k_inproj(const float* __restrict__ A,
    const u16* __restrict__ Bsw, const float* __restrict__ b_in,
    const float* __restrict__ g_in, const float* __restrict__ be_in,
    u16* __restrict__ xout, int N){
  __shared__ char smem[35840];
  u16* a_lds = (u16*)smem;                 // 4 KB frag-linear
  u16* b_lds = (u16*)(smem + 4096);        // 16 KB frag-linear
  u16* x_tile = (u16*)smem;                // 33792 B, reused after GEMM
  float* red = (float*)(smem + 33792);     // [64 rows][4 waves][2]
  const int t = threadIdx.x, w = t >> 6, l = t & 63, l15 = l & 15, quad = l >> 4;
  const int rowbase = blockIdx.x * 64;
  const int sm = t >> 2, sq = t & 3;
  const f4 z4 = {0.f, 0.f, 0.f, 0.f};
  f4 acc[4][4];
#pragma unroll
  for (int rt = 0; rt < 4; ++rt)
#pragma unroll
    for (int ct = 0; ct < 4; ++ct) acc[rt][ct] = z4;

  for (int kt = 0; kt < 24; ++kt){
    __syncthreads();
    { // stage A (fp32 -> bf16), frag-linear: thread t -> row sm, k-quad sq
      f4 a0 = z4, a1v = z4;
      int grow = rowbase + sm;
      if (grow < N){
        const float* ap = A + (size_t)grow * 768 + kt * 32 + sq * 8;
        a0 = *(const f4*)ap; a1v = *(const f4*)(ap + 4);
      }
      int4 pk; pk.x = (int)pack2(a0[0], a0[1]); pk.y = (int)pack2(a0[2], a0[3]);
      pk.z = (int)pack2(a1v[0], a1v[1]); pk.w = (int)pack2(a1v[2], a1v[3]);
      *(int4*)(a_lds + (size_t)(((sm >> 4) * 64 + sq * 16 + (sm & 15)) * 8)) = pk;
    }
    { // stage B chunk (16 KB contiguous)
      const int4* bs = (const int4*)(Bsw + (size_t)kt * 8192);
      int4* bd = (int4*)b_lds;
      bd[t] = bs[t]; bd[t + 256] = bs[t + 256]; bd[t + 512] = bs[t + 512]; bd[t + 768] = bs[t + 768];
    }
    __syncthreads();
    bf16x8 af[4], bfr[4];
#pragma unroll
    for (int rt = 0; rt < 4; ++rt) af[rt] = *(const bf16x8*)(a_lds + (rt * 64 + l) * 8);
#pragma unroll
    for (int ct = 0; ct < 4; ++ct) bfr[ct] = *(const bf16x8*)(b_lds + ((w * 4 + ct) * 64 + l) * 8);
#pragma unroll
    for (int rt = 0; rt < 4; ++rt)
#pragma unroll
      for (int ct = 0; ct < 4; ++ct)
        acc[rt][ct] = __builtin_amdgcn_mfma_f32_16x16x32_bf16(af[rt], bfr[ct], acc[rt][ct], 0, 0, 0);
  }
  // epilogue: +bias, LN over 256 cols (cross-wave via LDS), GELU, bf16 store
  float gv[4], bev[4];
#pragma unroll
  for (int ct = 0; ct < 4; ++ct){
    int col = w * 64 + ct * 16 + l15;
    float bc = b_in[col];
    gv[ct] = g_in[col]; bev[ct] = be_in[col];
#pragma unroll
    for (int rt = 0; rt < 4; ++rt)
#pragma unroll
      for (int r = 0; r < 4; ++r) acc[rt][ct][r] += bc;
  }
#pragma unroll
  for (int rt = 0; rt < 4; ++rt)
#pragma unroll
    for (int r = 0; r < 4; ++r){
      float s = 0.f, s2 = 0.f;
#pragma unroll
      for (int ct = 0; ct < 4; ++ct){ float v = acc[rt][ct][r]; s += v; s2 += v * v; }
#pragma unroll
      for (int m = 1; m < 16; m <<= 1){ s += __shfl_xor(s, m); s2 += __shfl_xor(s2, m); }
      if (l15 == 0){
        int row = rt * 16 + quad * 4 + r;          // C/D row = quad*4+reg (m89/m91)
        red[(row * 4 + w) * 2] = s; red[(row * 4 + w) * 2 + 1] = s2;
      }
    }
  __syncthreads();
#pragma unroll
  for (int rt = 0; rt < 4; ++rt)
#pragma unroll
    for (int r = 0; r < 4; ++r){
      int row = rt * 16 + quad * 4 + r;
      float s = 0.f, s2 = 0.f;
#pragma unroll
      for (int ww = 0; ww < 4; ++ww){ s += red[(row * 4 + ww) * 2]; s2 += red[(row * 4 + ww) * 2 + 1]; }
      float mu = s * (1.f / 256.f);
      float va = s2 * (1.f / 256.f) - mu * mu;
      float rstd = rsqrtf(va + 1e-5f);
#pragma unroll
      for (int ct = 0; ct < 4; ++ct){
        float v = (acc[rt][ct][r] - mu) * rstd * gv[ct] + bev[ct];
        v = gelu_f(v);
        x_tile[row * 264 + w * 64 + ct * 16 + l15] = f2bf(v);
      }
    }
  __syncthreads();
  { // coalesced bf16 store via LDS bounce
    int row = t >> 2, seg = t & 3;
    if (rowbase + row < N){
      u16* dst = xout + (size_t)(rowbase + row) * 256 + seg * 64;
      const u16* src = x_tile + row * 264 + seg * 64;
#pragma unroll
      for (int s8 = 0; s8 < 8; ++s8) *(int4*)(dst + s8 * 8) = *(const int4*)(src + s8 * 8);
    }
  }
}

// ---------------------------------------------------------------------------
// A2: K = x@Wk+bk (-> logits only), V = x@Wv+bv (-> bf16).  blockIdx.y = half.
// wave w == head w for the logits epilogue (cols w*64..w*64+63 = head w dims).
// ---------------------------------------------------------------------------
__global__ __launch_bounds__(256) void k_kv(const u16* __restrict__ x,
    const u16* __restrict__ Wkv_sw, const float* __restrict__ bk,
    const float* __restrict__ bv, const float* __restrict__ qc,
    float* __restrict__ logits, u16* __restrict__ Vout, int N){
  __shared__ char smem[35840];
  u16* a_lds = (u16*)smem;
  u16* b_lds = (u16*)(smem + 4096);
  u16* x_tile = (u16*)smem;
  const int half = blockIdx.y;
  const u16* Bsw = Wkv_sw + (size_t)half * 65536;
  const float* bias = half ? bv : bk;
  const int t = threadIdx.x, w = t >> 6, l = t & 63, l15 = l & 15, quad = l >> 4;
  const int rowbase = blockIdx.x * 64;
  const int sm = t >> 2, sq = t & 3;
  const f4 z4 = {0.f, 0.f, 0.f, 0.f};
  f4 acc[4][4];
#pragma unroll
  for (int rt = 0; rt < 4; ++rt)
#pragma unroll
    for (int ct = 0; ct < 4; ++ct) acc[rt][ct] = z4;

  for (int kt = 0; kt < 8; ++kt){
    __syncthreads();
    { // stage A from bf16 x, frag-linear
      int4 pk = {0, 0, 0, 0};
      int grow = rowbase + sm;
      if (grow < N) pk = *(const int4*)(x + (size_t)grow * 256 + kt * 32 + sq * 8);
      *(int4*)(a_lds + (size_t)(((sm >> 4) * 64 + sq * 16 + (sm & 15)) * 8)) = pk;
    }
    { const int4* bs = (const int4*)(Bsw + (size_t)kt * 8192);
      int4* bd = (int4*)b_lds;
      bd[t] = bs[t]; bd[t + 256] = bs[t + 256]; bd[t + 512] = bs[t + 512]; bd[t + 768] = bs[t + 768]; }
    __syncthreads();
    bf16x8 af[4], bfr[4];
#pragma unroll
    for (int rt = 0; rt < 4; ++rt) af[rt] = *(const bf16x8*)(a_lds + (rt * 64 + l) * 8);
#pragma unroll
    for (int ct = 0; ct < 4; ++ct) bfr[ct] = *(const bf16x8*)(b_lds + ((w * 4 + ct) * 64 + l) * 8);
#pragma unroll
    for (int rt = 0; rt < 4; ++rt)
#pragma unroll
      for (int ct = 0; ct < 4; ++ct)
        acc[rt][ct] = __builtin_amdgcn_mfma_f32_16x16x32_bf16(af[rt], bfr[ct], acc[rt][ct], 0, 0, 0);
  }
#pragma unroll
  for (int ct = 0; ct < 4; ++ct){
    int col = w * 64 + ct * 16 + l15;
    float bc = bias[col];
#pragma unroll
    for (int rt = 0; rt < 4; ++rt)
#pragma unroll
      for (int r = 0; r < 4; ++r) acc[rt][ct][r] += bc;
  }
  if (half == 0){
    float qv[4];
#pragma unroll
    for (int ct = 0; ct < 4; ++ct) qv[ct] = qc[w * 64 + ct * 16 + l15];
#pragma unroll
    for (int rt = 0; rt < 4; ++rt)
#pragma unroll
      for (int r = 0; r < 4; ++r){
        float p = 0.f;
#pragma unroll
        for (int ct = 0; ct < 4; ++ct) p += qv[ct] * acc[rt][ct][r];
#pragma unroll
        for (int m = 1; m < 16; m <<= 1) p += __shfl_xor(p, m);
        if (l15 == 0){
          int grow = rowbase + rt * 16 + quad * 4 + r;
          if (grow < N) logits[(size_t)grow * 4 + w] = 0.125f * p;
        }
      }
  } else {
    __syncthreads();   // all waves done with a/b frags before x_tile overwrite
#pragma unroll
    for (int rt = 0; rt < 4; ++rt)
#pragma unroll
      for (int r = 0; r < 4; ++r){
        int row = rt * 16 + quad * 4 + r;
#pragma unroll
        for (int ct = 0; ct < 4; ++ct)
          x_tile[row * 264 + w * 64 + ct * 16 + l15] = f2bf(acc[rt][ct][r]);
      }
    __syncthreads();
    int row = t >> 2, seg = t & 3;
    if (rowbase + row < N){
      u16* dst = Vout + (size_t)(rowbase + row) * 256 + seg * 64;
      const u16* src = x_tile + row * 264 + seg * 64;
#pragma unroll
      for (int s8 = 0; s8 < 8; ++s8) *(int4*)(dst + s8 * 8) = *(const int4*)(src + s8 * 8);
    }
  }
}

// ------------------------- segment pooling (counting sort) ------------------
__global__ void k_hist(const int* __restrict__ ci, int* __restrict__ count, int N){
  int n = blockIdx.x * 256 + threadIdx.x;
  if (n < N) atomicAdd(&count[ci[n]], 1);
}
__global__ void k_scan(const int* __restrict__ count, int* __restrict__ offsets, int C){
  __shared__ int parts[256];
  int t = threadIdx.x;
  int loc[8]; int s = 0;
#pragma unroll
  for (int i = 0; i < 8; ++i){ int idx = t * 8 + i; loc[i] = s; s += (idx < C) ? count[idx] : 0; }
  parts[t] = s; __syncthreads();
  for (int off = 1; off < 256; off <<= 1){
    int v = (t >= off) ? parts[t - off] : 0;
    __syncthreads();
    parts[t] += v;
    __syncthreads();
  }
  int base = parts[t] - s;
#pragma unroll
  for (int i = 0; i < 8; ++i){ int idx = t * 8 + i; if (idx < C) offsets[idx] = base + loc[i]; }
  if (t == 255) offsets[C] = parts[255];
}
__global__ void k_scatter(const int* __restrict__ ci, int* __restrict__ cursor,
      const int* __restrict__ offsets, int* __restrict__ perm, int N){
  int n = blockIdx.x * 256 + threadIdx.x;
  if (n < N){ int c = ci[n]; int p = atomicAdd(&cursor[c], 1); perm[offsets[c] + p] = n; }
}
// one block per commit: segment max -> exp -> weighted V sum (all in-block)
__global__ __launch_bounds__(256) void k_pool(const int* __restrict__ offsets,
    const int* __restrict__ perm, const float* __restrict__ logits,
    const u16* __restrict__ V, float* __restrict__ pooled, int C){
  __shared__ float red[256];
  __shared__ float mh[4];
  __shared__ int plds[256];
  int c = blockIdx.x, t = threadIdx.x;
  int base = offsets[c], cnt = offsets[c + 1] - base;
  if (cnt == 0){ pooled[(size_t)c * 256 + t] = 0.f; return; }
  { int h = t & 3; float mx = -1e30f;
    for (int i = t >> 2; i < cnt; i += 64){ int n = perm[base + i]; mx = fmaxf(mx, logits[(size_t)n * 4 + h]); }
    red[t] = mx; }
  __syncthreads();
  if (t < 4){ float mx = -1e30f; for (int k = 0; k < 64; ++k) mx = fmaxf(mx, red[k * 4 + t]); mh[t] = mx; }
  __syncthreads();
  int h = t >> 6;
  float mhh = mh[h];
  float macc = 0.f, sacc = 0.f;
  for (int c0 = 0; c0 < cnt; c0 += 256){
    if (c0 + t < cnt) plds[t] = perm[base + c0 + t];
    __syncthreads();
    int lim = min(256, cnt - c0);
    for (int ii = 0; ii < lim; ++ii){
      int n = plds[ii];
      float e = expf(logits[(size_t)n * 4 + h] - mhh);
      sacc += e;
      macc += e * bf2f(V[(size_t)n * 256 + t]);
    }
    __syncthreads();
  }
  pooled[(size_t)c * 256 + t] = macc / sacc;
}

// ------------------- C-scale row GEMM + bias/res/GELU/LN --------------------
template<int IN, int OUT, int CPT, bool GEL, bool LNRM, bool RES>
__global__ __launch_bounds__(256) void k_rowffn(const float* __restrict__ in,
    const float* __restrict__ W, const float* __restrict__ bias,
    const float* __restrict__ res, const float* __restrict__ g,
    const float* __restrict__ bb, float* __restrict__ out, int C){
  __shared__ float rows_lds[4 * IN];
  __shared__ float wred[4][4][2];
  const int t = threadIdx.x;
  const int r0 = blockIdx.x * 4;
  const int NF4 = IN / 4;
  for (int i = t; i < 4 * NF4; i += 256){
    int row = i / NF4, seg = i % NF4;
    f4 v = {0.f, 0.f, 0.f, 0.f};
    if (r0 + row < C) v = *(const f4*)(in + (size_t)(r0 + row) * IN + seg * 4);
    *(f4*)&rows_lds[row * IN + seg * 4] = v;
  }
  __syncthreads();
  float acc[4][CPT];
#pragma unroll
  for (int r = 0; r < 4; ++r)
#pragma unroll
    for (int cc = 0; cc < CPT; ++cc) acc[r][cc] = 0.f;
  const bool active = (OUT >= 256) || (t < OUT);
  if (active){
    for (int i = 0; i < IN; ++i){
      float rv0 = rows_lds[i], rv1 = rows_lds[IN + i], rv2 = rows_lds[2 * IN + i], rv3 = rows_lds[3 * IN + i];
#pragma unroll
      for (int cc = 0; cc < CPT; ++cc){
        float wv = W[(size_t)i * OUT + t + cc * 256];
        acc[0][cc] += rv0 * wv; acc[1][cc] += rv1 * wv;
        acc[2][cc] += rv2 * wv; acc[3][cc] += rv3 * wv;
      }
    }
#pragma unroll
    for (int r = 0; r < 4; ++r)
#pragma unroll
      for (int cc = 0; cc < CPT; ++cc){
        int col = t + cc * 256;
        float v = acc[r][cc] + bias[col];
        if (RES) v += res[(size_t)(r0 + r) * OUT + col];
        if (GEL) v = gelu_f(v);
        acc[r][cc] = v;
      }
  }
  if (LNRM){ // only instantiated with OUT==256, CPT==1
    const int wv_ = t >> 6, ln = t & 63;
#pragma unroll
    for (int r = 0; r < 4; ++r){
      float s = acc[r][0], s2 = acc[r][0] * acc[r][0];
      for (int m = 1; m < 64; m <<= 1){ s += __shfl_xor(s, m); s2 += __shfl_xor(s2, m); }
      if (ln == 0){ wred[wv_][r][0] = s; wred[wv_][r][1] = s2; }
    }
    __syncthreads();
#pragma unroll
    for (int r = 0; r < 4; ++r){
      float s = 0.f, s2 = 0.f;
#pragma unroll
      for (int k = 0; k < 4; ++k){ s += wred[k][r][0]; s2 += wred[k][r][1]; }
      float mu = s * (1.f / OUT), va = s2 * (1.f / OUT) - mu * mu, rstd = rsqrtf(va + 1e-5f);
      acc[r][0] = (acc[r][0] - mu) * rstd * g[t] + bb[t];
    }
  }
  if (active){
#pragma unroll
    for (int r = 0; r < 4; ++r)
      if (r0 + r < C)
#pragma unroll
        for (int cc = 0; cc < CPT; ++cc)
          out[(size_t)(r0 + r) * OUT + t + cc * 256] = acc[r][cc];
  }
}

__global__ void k_transpose(const float* __restrict__ src, float* __restrict__ dst, int C){
  __shared__ float tile[32][33];
  int tx = threadIdx.x, ty = threadIdx.y;
  int rb = blockIdx.x * 32, cb = blockIdx.y * 32;
#pragma unroll
  for (int i = 0; i < 4; ++i){
    int r = rb + ty * 4 + i;
    tile[ty * 4 + i][tx] = (r < C) ? src[(size_t)r * 256 + cb + tx] : 0.f;
  }
  __syncthreads();
#pragma unroll
  for (int i = 0; i < 4; ++i){
    int c = cb + ty * 4 + i;
    int r = rb + tx;
    if (r < C) dst[(size_t)c * C + r] = tile[tx][ty * 4 + i];
  }
}

// --------------------- fp32 flash attention (H=4, D=64) ---------------------
// grid (ceil(C/64), H). block 256. wave w: q rows w*16..w*16+15; lane: row pair
// rp=l>>3 and key group / dim group g8=l&7.
__global__ __launch_bounds__(256) void k_attn(const float* __restrict__ qb,
    const float* __restrict__ kT, const float* __restrict__ vb,
    float* __restrict__ o, int C){
  __shared__ float q_lds[64 * 68];
  __shared__ float k_lds[64 * 36];   // [d][j] so score k-reads are f4 over keys
  __shared__ float v_lds[32 * 68];   // [j][d]
  __shared__ float p_lds[64 * 33];   // wave-private row blocks
  const int h = blockIdx.y;
  const int qbase = blockIdx.x * 64;
  const int t = threadIdx.x, w = t >> 6, l = t & 63;
  const int rp = l >> 3, g8 = l & 7;
  const int j4 = g8 * 4, d0 = g8 * 8;
  const int r0 = w * 16 + rp * 2, r1 = r0 + 1;
  const f4 z4 = {0.f, 0.f, 0.f, 0.f};
  { // stage q once
    int r = t >> 2; int cb = (t & 3) * 16;
    int grow = qbase + r;
#pragma unroll
    for (int s = 0; s < 4; ++s){
      f4 v = z4;
      if (grow < C) v = *(const f4*)(qb + (size_t)grow * 256 + h * 64 + cb + s * 4);
      *(f4*)&q_lds[r * 68 + cb + s * 4] = v;
    }
  }
  float m0 = -1e30f, m1 = -1e30f, l0 = 0.f, l1 = 0.f;
  f4 a00 = z4, a01 = z4, a10 = z4, a11 = z4;
  for (int ck = 0; ck < C; ck += 32){
    __syncthreads();
    { // stage k chunk transposed: k_lds[d][j]
      int d = t >> 2, jb = (t & 3) * 8;
      const float* kp = kT + (size_t)(h * 64 + d) * C + ck + jb;
      if (ck + 32 <= C){
        *(f4*)&k_lds[d * 36 + jb] = *(const f4*)kp;
        *(f4*)&k_lds[d * 36 + jb + 4] = *(const f4*)(kp + 4);
      } else {
        for (int i = 0; i < 8; ++i) k_lds[d * 36 + jb + i] = (ck + jb + i < C) ? kp[i] : 0.f;
      }
    }
    { // stage v chunk: v_lds[j][d]
      int j = t >> 3, db = (t & 7) * 8;
      f4 v0 = z4, v1 = z4;
      if (ck + j < C){
        const float* vp = vb + (size_t)(ck + j) * 256 + h * 64 + db;
        v0 = *(const f4*)vp; v1 = *(const f4*)(vp + 4);
      }
      *(f4*)&v_lds[j * 68 + db] = v0; *(f4*)&v_lds[j * 68 + db + 4] = v1;
    }
    __syncthreads();
    float s0[4] = {0.f, 0.f, 0.f, 0.f}, s1[4] = {0.f, 0.f, 0.f, 0.f};
#pragma unroll 4
    for (int d = 0; d < 64; ++d){
      float q0v = q_lds[r0 * 68 + d], q1v = q_lds[r1 * 68 + d];
      f4 kk = *(const f4*)&k_lds[d * 36 + j4];
      s0[0] += q0v * kk[0]; s0[1] += q0v * kk[1]; s0[2] += q0v * kk[2]; s0[3] += q0v * kk[3];
      s1[0] += q1v * kk[0]; s1[1] += q1v * kk[1]; s1[2] += q1v * kk[2]; s1[3] += q1v * kk[3];
    }
#pragma unroll
    for (int i = 0; i < 4; ++i){
      bool oob = (ck + j4 + i) >= C;
      s0[i] = oob ? -1e30f : s0[i] * 0.125f;
      s1[i] = oob ? -1e30f : s1[i] * 0.125f;
    }
    float mx0 = fmaxf(fmaxf(s0[0], s0[1]), fmaxf(s0[2], s0[3]));
    float mx1 = fmaxf(fmaxf(s1[0], s1[1]), fmaxf(s1[2], s1[3]));
#pragma unroll
    for (int m = 1; m < 8; m <<= 1){ mx0 = fmaxf(mx0, __shfl_xor(mx0, m)); mx1 = fmaxf(mx1, __shfl_xor(mx1, m)); }
    float nm0 = fmaxf(m0, mx0), nm1 = fmaxf(m1, mx1);
    float al0 = expf(m0 - nm0), al1 = expf(m1 - nm1);
    float p0[4], p1[4]; float ps0 = 0.f, ps1 = 0.f;
#pragma unroll
    for (int i = 0; i < 4; ++i){
      p0[i] = expf(s0[i] - nm0); ps0 += p0[i];
      p1[i] = expf(s1[i] - nm1); ps1 += p1[i];
    }
#pragma unroll
    for (int m = 1; m < 8; m <<= 1){ ps0 += __shfl_xor(ps0, m); ps1 += __shfl_xor(ps1, m); }
    l0 = l0 * al0 + ps0; l1 = l1 * al1 + ps1; m0 = nm0; m1 = nm1;
    a00 *= al0; a01 *= al0; a10 *= al1; a11 *= al1;
#pragma unroll
    for (int i = 0; i < 4; ++i){ p_lds[r0 * 33 + j4 + i] = p0[i]; p_lds[r1 * 33 + j4 + i] = p1[i]; }
#pragma unroll 4
    for (int j = 0; j < 32; ++j){
      float pj0 = p_lds[r0 * 33 + j], pj1 = p_lds[r1 * 33 + j];
      f4 va = *(const f4*)&v_lds[j * 68 + d0];
      f4 vb4 = *(const f4*)&v_lds[j * 68 + d0 + 4];
      a00 += pj0 * va; a01 += pj0 * vb4; a10 += pj1 * va; a11 += pj1 * vb4;
    }
  }
  int gr0 = qbase + r0, gr1 = qbase + r1;
  if (gr0 < C){
    float inv = 1.f / l0;
    *(f4*)(o + (size_t)gr0 * 256 + h * 64 + d0) = a00 * inv;
    *(f4*)(o + (size_t)gr0 * 256 + h * 64 + d0 + 4) = a01 * inv;
  }
  if (gr1 < C){
    float inv = 1.f / l1;
    *(f4*)(o + (size_t)gr1 * 256 + h * 64 + d0) = a10 * inv;
    *(f4*)(o + (size_t)gr1 * 256 + h * 64 + d0 + 4) = a11 * inv;
  }
}

__global__ void k_head2(const float* __restrict__ h1, const float* __restrict__ W2,
                        const float* __restrict__ b2, float* __restrict__ out, int C){
  int r = blockIdx.x * 256 + threadIdx.x;
  if (r < C){
    float s = b2[0];
    for (int i = 0; i < 128; ++i) s += h1[(size_t)r * 128 + i] * W2[i];
    out[r] = s;
  }
}

// ---------------------------------------------------------------------------
extern "C" void kernel_launch(void* const* d_in, const int* in_sizes, int n_in,
                              void* d_out, int out_size, void* d_ws, size_t ws_size,
                              hipStream_t stream){
  const float* node_emb = (const float*)d_in[0];
  const int*   ci       = (const int*)d_in[1];
  const float* W_in  = (const float*)d_in[3];
  const float* b_in  = (const float*)d_in[4];
  const float* g_in  = (const float*)d_in[5];
  const float* be_in = (const float*)d_in[6];
  const float* q_commit = (const float*)d_in[7];
  const float* Wk = (const float*)d_in[8];
  const float* bk = (const float*)d_in[9];
  const float* Wv = (const float*)d_in[10];
  const float* bv = (const float*)d_in[11];
  const float* Wo_pool = (const float*)d_in[12];
  const float* bo_pool = (const float*)d_in[13];
  const float* g_pool = (const float*)d_in[14];
  const float* b_pool = (const float*)d_in[15];
  const float* Wq_t = (const float*)d_in[16];
  const float* bq_t = (const float*)d_in[17];
  const float* Wk_t = (const float*)d_in[18];
  const float* bk_t = (const float*)d_in[19];
  const float* Wv_t = (const float*)d_in[20];
  const float* bv_t = (const float*)d_in[21];
  const float* Wo_t = (const float*)d_in[22];
  const float* bo_t = (const float*)d_in[23];
  const float* g1 = (const float*)d_in[24];
  const float* b1 = (const float*)d_in[25];
  const float* W_ff1 = (const float*)d_in[26];
  const float* b_ff1 = (const float*)d_in[27];
  const float* W_ff2 = (const float*)d_in[28];
  const float* b_ff2 = (const float*)d_in[29];
  const float* g2 = (const float*)d_in[30];
  const float* b2 = (const float*)d_in[31];
  const float* W_h1 = (const float*)d_in[32];
  const float* b_h1 = (const float*)d_in[33];
  const float* W_h2 = (const float*)d_in[34];
  const float* b_h2 = (const float*)d_in[35];
  const int N = in_sizes[1];     // commit_indices length
  const int C = out_size;        // num_commits

  char* ws = (char*)d_ws;
  size_t off = 0;
  auto alc = [&](size_t bytes)->char*{
    char* p = ws + off;
    off += (bytes + 255) & ~(size_t)255;
    return p;
  };
  u16* xbf      = (u16*)alc((size_t)N * 256 * 2);
  u16* Vbf      = (u16*)alc((size_t)N * 256 * 2);
  float* logits = (float*)alc((size_t)N * 4 * 4);
  int* count    = (int*)alc((size_t)2 * C * 4);
  int* cursor   = count + C;
  int* offsets  = (int*)alc((size_t)(C + 1) * 4);
  int* perm     = (int*)alc((size_t)N * 4);
  float* pooled = (float*)alc((size_t)C * 256 * 4);
  float* emb    = (float*)alc((size_t)C * 256 * 4);
  float* qb     = (float*)alc((size_t)C * 256 * 4);
  float* kb     = (float*)alc((size_t)C * 256 * 4);
  float* vbuf   = (float*)alc((size_t)C * 256 * 4);
  float* kTb    = (float*)alc((size_t)C * 256 * 4);
  float* attnout= (float*)alc((size_t)C * 256 * 4);
  float* ybuf   = (float*)alc((size_t)C * 256 * 4);
  float* ffb    = (float*)alc((size_t)C * 1024 * 4);
  float* y2b    = (float*)alc((size_t)C * 256 * 4);
  float* h1b    = (float*)alc((size_t)C * 128 * 4);
  u16* Win_sw   = (u16*)alc((size_t)24 * 16 * 64 * 8 * 2);
  u16* Wkv_sw   = (u16*)alc((size_t)2 * 8 * 16 * 64 * 8 * 2);

  hipMemsetAsync(count, 0, (size_t)2 * C * 4, stream);
  k_swizzle<<<160, 256, 0, stream>>>(W_in, Wk, Wv, Win_sw, Wkv_sw);
  k_inproj<<<(N + 63) / 64, 256, 0, stream>>>(node_emb, Win_sw, b_in, g_in, be_in, xbf, N);
  k_kv<<<dim3((N + 63) / 64, 2), 256, 0, stream>>>(xbf, Wkv_sw, bk, bv, q_commit, logits, Vbf, N);
  k_hist<<<(N + 255) / 256, 256, 0, stream>>>(ci, count, N);
  k_scan<<<1, 256, 0, stream>>>(count, offsets, C);
  k_scatter<<<(N + 255) / 256, 256, 0, stream>>>(ci, cursor, offsets, perm, N);
  k_pool<<<C, 256, 0, stream>>>(offsets, perm, logits, Vbf, pooled, C);
  int rb = (C + 3) / 4;
  k_rowffn<256, 256, 1, false, true, false><<<rb, 256, 0, stream>>>(pooled, Wo_pool, bo_pool, nullptr, g_pool, b_pool, emb, C);
  k_rowffn<256, 256, 1, false, false, false><<<rb, 256, 0, stream>>>(emb, Wq_t, bq_t, nullptr, nullptr, nullptr, qb, C);
  k_rowffn<256, 256, 1, false, false, false><<<rb, 256, 0, stream>>>(emb, Wk_t, bk_t, nullptr, nullptr, nullptr, kb, C);
  k_rowffn<256, 256, 1, false, false, false><<<rb, 256, 0, stream>>>(emb, Wv_t, bv_t, nullptr, nullptr, nullptr, vbuf, C);
  k_transpose<<<dim3((C + 31) / 32, 8), dim3(32, 8), 0, stream>>>(kb, kTb, C);
  k_attn<<<dim3((C + 63) / 64, 4), 256, 0, stream>>>(qb, kTb, vbuf, attnout, C);
  k_rowffn<256, 256, 1, false, true, true><<<rb, 256, 0, stream>>>(attnout, Wo_t, bo_t, emb, g1, b1, ybuf, C);
  k_rowffn<256, 1024, 4, true, false, false><<<rb, 256, 0, stream>>>(ybuf, W_ff1, b_ff1, nullptr, nullptr, nullptr, ffb, C);
  k_rowffn<1024, 256, 1, false, true, true><<<rb, 256, 0, stream>>>(ffb, W_ff2, b_ff2, ybuf, g2, b2, y2b, C);
  k_rowffn<256, 128, 1, true, false, false><<<rb, 256, 0, stream>>>(y2b, W_h1, b_h1, nullptr, nullptr, nullptr, h1b, C);
  k_head2<<<(C + 255) / 256, 256, 0, stream>>>(h1b, W_h2, b_h2, (float*)d_out, C);
}